// Round 25
// baseline (74.378 us; speedup 1.0000x reference)
//
#include <hip/hip_runtime.h>
#include <hip/hip_bf16.h>

constexpr int B  = 256;
constexpr int E  = 16384;
constexpr int M  = 65536;
constexpr int H  = 128;
constexpr int NH = 4;
constexpr int HD = 32;
constexpr int LQ = 128;
constexpr int LK = 384;

// bf16 weight buffer offsets (elements)
constexpr int WQ_OFF  = 0;
constexpr int WK_OFF  = 16384;
constexpr int WV_OFF  = 32768;
constexpr int OPW_OFF = 49152;
constexpr int W1_OFF  = 65536;
constexpr int W2_OFF  = 98304;
constexpr int W_TOTAL = 131072;

typedef __attribute__((ext_vector_type(8))) short bf16x8;
typedef __attribute__((ext_vector_type(8))) unsigned short u16x8;
typedef __attribute__((ext_vector_type(4))) float f32x4;

__device__ __forceinline__ ushort f2bf(float x) {
  union { float f; unsigned u; } v; v.f = x;
  unsigned r = (v.u + 0x7FFFu + ((v.u >> 16) & 1u)) >> 16;
  return (ushort)r;
}
__device__ __forceinline__ unsigned pack2bf(float a, float b) {
  return (unsigned)f2bf(a) | ((unsigned)f2bf(b) << 16);
}

// ---------------- K1: bf16 weight prep ----------------
__global__ __launch_bounds__(256) void k_prep(
    const float* __restrict__ in_proj_w, const float* __restrict__ opw,
    const float* __restrict__ w1, const float* __restrict__ w2,
    ushort* __restrict__ Wb) {
  int i = (blockIdx.x * 256 + threadIdx.x) * 4;
  if (i < W_TOTAL) {
    float4 v;
    if (i < OPW_OFF)      v = *(const float4*)(in_proj_w + i);
    else if (i < W1_OFF)  v = *(const float4*)(opw + (i - OPW_OFF));
    else if (i < W2_OFF)  v = *(const float4*)(w1 + (i - W1_OFF));
    else                  v = *(const float4*)(w2 + (i - W2_OFF));
    ushort4 o; o.x = f2bf(v.x); o.y = f2bf(v.y); o.z = f2bf(v.z); o.w = f2bf(v.w);
    *(ushort4*)(Wb + i) = o;
  }
}

// ---------------- K2: dense Q/K/V projection, head-major output ----------------
// grid E/64, 256 threads = 4 waves. Wave owns 2 row-tiles x ct-half;
// 2 independent MFMA chains per ct. Output layout: X[h][e][d].
__global__ __launch_bounds__(256) void k_proj_all(
    const float* __restrict__ edge_attr, const ushort* __restrict__ Wb,
    const float* __restrict__ in_proj_b,
    ushort* __restrict__ Qh, ushort* __restrict__ Kh, ushort* __restrict__ Vh) {
  constexpr int IP = 136;
  __shared__ ushort inL[64 * IP];   // 17408 B
  const int t = threadIdx.x;
  const int row0 = blockIdx.x * 64;
  for (int idx = t; idx < 64 * 32; idx += 256) {
    int r = idx >> 5, c = idx & 31;
    float4 v = ((const float4*)(edge_attr + (size_t)(row0 + r) * H))[c];
    ushort4 o; o.x = f2bf(v.x); o.y = f2bf(v.y); o.z = f2bf(v.z); o.w = f2bf(v.w);
    *(ushort4*)(inL + r * IP + c * 4) = o;
  }
  __syncthreads();
  const int w = t >> 6, lane = t & 63, g = lane >> 4, l15 = lane & 15;
  const int wr = (w & 1) * 16, ch = w >> 1;   // row-tile base (within 32), ct-half
  bf16x8 a[2][4];
#pragma unroll
  for (int rt = 0; rt < 2; rt++)
#pragma unroll
    for (int kc = 0; kc < 4; kc++)
      a[rt][kc] = *(const bf16x8*)(inL + (rt * 32 + wr + l15) * IP + kc * 32 + g * 8);
  const int rowA = row0 + wr + l15;
  const int rowB = row0 + 32 + wr + l15;
#pragma unroll
  for (int p = 0; p < 3; p++) {
    const float* bias = in_proj_b + p * H;
    ushort* dst = (p == 0) ? Qh : (p == 1) ? Kh : Vh;
#pragma unroll
    for (int ci = 0; ci < 4; ci++) {
      int ct = ch * 4 + ci;
      f32x4 acc0 = {0.f, 0.f, 0.f, 0.f}, acc1 = {0.f, 0.f, 0.f, 0.f};
#pragma unroll
      for (int kc = 0; kc < 4; kc++) {
        bf16x8 bw = *(const bf16x8*)(Wb + p * 16384 + (size_t)(ct * 16 + l15) * H + kc * 32 + g * 8);
        acc0 = __builtin_amdgcn_mfma_f32_16x16x32_bf16(bw, a[0][kc], acc0, 0, 0, 0);
        acc1 = __builtin_amdgcn_mfma_f32_16x16x32_bf16(bw, a[1][kc], acc1, 0, 0, 0);
      }
      int oc = ct * 16 + 4 * g;
      float4 bb = *(const float4*)(bias + oc);
      ushort4 v0, v1;
      v0.x = f2bf(acc0[0] + bb.x); v0.y = f2bf(acc0[1] + bb.y);
      v0.z = f2bf(acc0[2] + bb.z); v0.w = f2bf(acc0[3] + bb.w);
      v1.x = f2bf(acc1[0] + bb.x); v1.y = f2bf(acc1[1] + bb.y);
      v1.z = f2bf(acc1[2] + bb.z); v1.w = f2bf(acc1[3] + bb.w);
      size_t hb = (size_t)(oc >> 5) * E * HD + (oc & 31);
      *(ushort4*)(dst + hb + (size_t)rowA * HD) = v0;
      *(ushort4*)(dst + hb + (size_t)rowB * HD) = v1;
    }
  }
}

// ---------------- K3: flash attention; K from global, V^T in LDS ----------------
// grid (B, NH), 256 threads = 4 waves. Segment bounds via inline binary search.
__global__ __launch_bounds__(256, 4) void k_attn_g(
    const ushort* __restrict__ Qh, const ushort* __restrict__ Kh,
    const ushort* __restrict__ Vh, const int* __restrict__ iel,
    const int* __restrict__ eb, const int* __restrict__ ieb,
    const float* __restrict__ in_proj_b, ushort* __restrict__ CtxB) {
  constexpr int VP = 388;
  __shared__ ushort VTl[HD * VP];              // 24832 B
  __shared__ int srcL[LK];                     //  1536 B
  __shared__ int meta[4];

  const int b = blockIdx.x, h = blockIdx.y;
  const int t = threadIdx.x;
  if (t < 4) {
    int target = (t & 1) ? b + 1 : b;
    const int* arr = (t < 2) ? eb : ieb;
    int n = (t < 2) ? E : M;
    int lo = 0, hi = n;
    while (lo < hi) { int mid = (lo + hi) >> 1; if (arr[mid] < target) lo = mid + 1; else hi = mid; }
    meta[t] = lo;
  }
  __syncthreads();
  const int q0 = meta[0], lenq = meta[1] - meta[0];
  const int k0 = meta[2], lenk = meta[3] - meta[2];
  const int nq = lenq < LQ ? lenq : LQ;
  const int nk = lenk < LK ? lenk : LK;
  const int nkc = (nk + 63) & ~63;
  const int nqt = (nq + 15) >> 4;

  const int w = t >> 6, lane = t & 63, g = lane >> 4, l15 = lane & 15;
  const ushort* Qhh = Qh + (size_t)h * E * HD;
  const ushort* Khh = Kh + (size_t)h * E * HD;
  const ushort* Vhh = Vh + (size_t)h * E * HD;
  const int chb = h * HD;

  // resolve gather indices (with LK clip)
  for (int idx = t; idx < nk; idx += 256) {
    int kj = k0 + idx;
    if (lenk > LK && idx == LK - 1) kj = k0 + lenk - 1;
    srcL[idx] = iel[kj];
  }
  __syncthreads();
  // stage V head-slices transposed (indices from srcL)
  for (int idx = t; idx < nk * 4; idx += 256) {
    int row = idx >> 2, c = idx & 3;
    int src = srcL[row];
    u16x8 v = *(const u16x8*)(Vhh + (size_t)src * HD + c * 8);
#pragma unroll
    for (int j = 0; j < 8; j++) VTl[(c * 8 + j) * VP + row] = v[j];
  }
  for (int idx = t; idx < ((nkc - nk) << 5); idx += 256) {
    int d = idx & 31, k = nk + (idx >> 5);
    VTl[d * VP + k] = 0;
  }
  __syncthreads();

  const float scale = 0.17677669529663687f;  // 1/sqrt(32)
  for (int qt = w; qt < nqt; qt += 4) {
    int slot = qt * 16 + l15;
    bool valid = slot < nq;
    int src = q0 + slot;
    if (lenq > LQ && slot == LQ - 1) src = q0 + lenq - 1;
    if (!valid) src = q0;
    bf16x8 bq = *(const bf16x8*)(Qhh + (size_t)src * HD + g * 8);

    f32x4 o0 = {0.f, 0.f, 0.f, 0.f}, o1 = {0.f, 0.f, 0.f, 0.f};
    float m = -3.0e38f, s = 0.f;
    for (int kc = 0; kc < nk; kc += 64) {
      int r0 = kc + l15, r1 = kc + 16 + l15, r2 = kc + 32 + l15, r3 = kc + 48 + l15;
      int s0_ = (r0 < nk) ? srcL[r0] : 0;
      int s1_ = (r1 < nk) ? srcL[r1] : 0;
      int s2_ = (r2 < nk) ? srcL[r2] : 0;
      int s3_ = (r3 < nk) ? srcL[r3] : 0;
      bf16x8 a0 = *(const bf16x8*)(Khh + (size_t)s0_ * HD + g * 8);
      bf16x8 a1 = *(const bf16x8*)(Khh + (size_t)s1_ * HD + g * 8);
      bf16x8 a2 = *(const bf16x8*)(Khh + (size_t)s2_ * HD + g * 8);
      bf16x8 a3 = *(const bf16x8*)(Khh + (size_t)s3_ * HD + g * 8);
      f32x4 z = {0.f, 0.f, 0.f, 0.f};
      f32x4 st0 = __builtin_amdgcn_mfma_f32_16x16x32_bf16(a0, bq, z, 0, 0, 0);
      f32x4 st1 = __builtin_amdgcn_mfma_f32_16x16x32_bf16(a1, bq, z, 0, 0, 0);
      f32x4 st2 = __builtin_amdgcn_mfma_f32_16x16x32_bf16(a2, bq, z, 0, 0, 0);
      f32x4 st3 = __builtin_amdgcn_mfma_f32_16x16x32_bf16(a3, bq, z, 0, 0, 0);
      float p[16];
#pragma unroll
      for (int r = 0; r < 4; r++) {
        p[r]      = (kc + 4 * g + r < nk)      ? st0[r] * scale : -1e30f;
        p[4 + r]  = (kc + 16 + 4 * g + r < nk) ? st1[r] * scale : -1e30f;
        p[8 + r]  = (kc + 32 + 4 * g + r < nk) ? st2[r] * scale : -1e30f;
        p[12 + r] = (kc + 48 + 4 * g + r < nk) ? st3[r] * scale : -1e30f;
      }
      float pm = p[0];
#pragma unroll
      for (int r = 1; r < 16; r++) pm = fmaxf(pm, p[r]);
      pm = fmaxf(pm, __shfl_xor(pm, 16));
      pm = fmaxf(pm, __shfl_xor(pm, 32));
      float mn = fmaxf(m, pm);
      float corr = __expf(m - mn);
      float rs = 0.f;
#pragma unroll
      for (int r = 0; r < 16; r++) { p[r] = __expf(p[r] - mn); rs += p[r]; }
      rs += __shfl_xor(rs, 16);
      rs += __shfl_xor(rs, 32);
      s = s * corr + rs;
      m = mn;
      unsigned pkw[4][2];
#pragma unroll
      for (int i = 0; i < 4; i++) {
        pkw[i][0] = pack2bf(p[4 * i + 0], p[4 * i + 1]);
        pkw[i][1] = pack2bf(p[4 * i + 2], p[4 * i + 3]);
      }
      union { int i[4]; bf16x8 v; } pb0, pb1;
#pragma unroll
      for (int j = 0; j < 4; j++) {
        int sl = (2 * (g & 1) + (j >> 1)) * 16 + l15;
        int a_ = __shfl((int)pkw[0][j & 1], sl);
        int b_ = __shfl((int)pkw[1][j & 1], sl);
        int c_ = __shfl((int)pkw[2][j & 1], sl);
        int d_ = __shfl((int)pkw[3][j & 1], sl);
        pb0.i[j] = (g < 2) ? a_ : b_;
        pb1.i[j] = (g < 2) ? c_ : d_;
      }
      bf16x8 av00 = *(const bf16x8*)(VTl + l15 * VP + kc + 8 * g);
      bf16x8 av01 = *(const bf16x8*)(VTl + l15 * VP + kc + 32 + 8 * g);
      bf16x8 av10 = *(const bf16x8*)(VTl + (16 + l15) * VP + kc + 8 * g);
      bf16x8 av11 = *(const bf16x8*)(VTl + (16 + l15) * VP + kc + 32 + 8 * g);
#pragma unroll
      for (int r = 0; r < 4; r++) { o0[r] *= corr; o1[r] *= corr; }
      o0 = __builtin_amdgcn_mfma_f32_16x16x32_bf16(av00, pb0.v, o0, 0, 0, 0);
      o0 = __builtin_amdgcn_mfma_f32_16x16x32_bf16(av01, pb1.v, o0, 0, 0, 0);
      o1 = __builtin_amdgcn_mfma_f32_16x16x32_bf16(av10, pb0.v, o1, 0, 0, 0);
      o1 = __builtin_amdgcn_mfma_f32_16x16x32_bf16(av11, pb1.v, o1, 0, 0, 0);
    }
    if (valid) {
      int qi = q0 + slot;
      if (lenq > LQ && slot == LQ - 1) qi = q0 + lenq - 1;
      ushort* outp = CtxB + (size_t)qi * H + chb;
      if (nk > 0) {
        float inv = 1.f / s;
        ushort4 v0, v1;
#pragma unroll
        for (int r = 0; r < 4; r++) { ((ushort*)&v0)[r] = f2bf(o0[r] * inv); ((ushort*)&v1)[r] = f2bf(o1[r] * inv); }
        *(ushort4*)(outp + 4 * g) = v0;
        *(ushort4*)(outp + 16 + 4 * g) = v1;
      } else {
        const float* bv = in_proj_b + 2 * H + chb;
        ushort4 v0, v1;
#pragma unroll
        for (int r = 0; r < 4; r++) { ((ushort*)&v0)[r] = f2bf(bv[4 * g + r]); ((ushort*)&v1)[r] = f2bf(bv[16 + 4 * g + r]); }
        *(ushort4*)(outp + 4 * g) = v0;
        *(ushort4*)(outp + 16 + 4 * g) = v1;
      }
    }
  }
}

// ---------------- K4: out-proj + residual + FFN (32-row blocks, 2 row-tiles/wave) ----------------
__global__ __launch_bounds__(256) void k_out_ffn_mfma(
    const ushort* __restrict__ CtxB, const float* __restrict__ edge_attr,
    const int* __restrict__ eb, const ushort* __restrict__ Wb,
    const float* __restrict__ opb, const float* __restrict__ b1,
    const float* __restrict__ b2, float* __restrict__ out) {
  constexpr int IP = 136;  // K=128 pitch
  constexpr int HP = 264;  // K=256 pitch
  __shared__ ushort attB[32 * IP];  // ctx staging, then att bf16 (8704 B)
  __shared__ ushort h1L[32 * HP];   // h1 bf16 (16896 B)
  __shared__ int srcRow[32];
  const int t = threadIdx.x;
  const int row0 = blockIdx.x * 32;

  if (t < 32) {
    int i = row0 + t;
    int bb = eb[i];
    int lo = 0, hi = E;
    while (lo < hi) { int mid = (lo + hi) >> 1; if (eb[mid] < bb) lo = mid + 1; else hi = mid; }
    int qq0 = lo;
    hi = E;
    while (lo < hi) { int mid = (lo + hi) >> 1; if (eb[mid] < bb + 1) lo = mid + 1; else hi = mid; }
    int lenq = lo - qq0;
    int src = i;
    if (lenq > LQ && (i - qq0) >= LQ - 1) src = qq0 + lenq - 1;
    srcRow[t] = src;
  }
  __syncthreads();

  for (int idx = t; idx < 32 * 16; idx += 256) {
    int r = idx >> 4, c = idx & 15;
    *(u16x8*)(attB + r * IP + c * 8) = *(const u16x8*)(CtxB + (size_t)srcRow[r] * H + c * 8);
  }
  __syncthreads();

  const int w = t >> 6, lane = t & 63, g = lane >> 4, l15 = lane & 15;
  bf16x8 ca[2][4];
#pragma unroll
  for (int rt = 0; rt < 2; rt++)
#pragma unroll
    for (int kc = 0; kc < 4; kc++)
      ca[rt][kc] = *(const bf16x8*)(attB + (rt * 16 + l15) * IP + kc * 32 + g * 8);
  __syncthreads();   // attB free for att writes

  // phase A: att = ctx @ opw^T + opb + edge_attr  (2 ct tiles x 2 row-tiles)
  float att[2][2][4];   // [ci][rt][r]
#pragma unroll
  for (int ci = 0; ci < 2; ci++) {
    int ct = w * 2 + ci;
    f32x4 acc0 = {0.f, 0.f, 0.f, 0.f}, acc1 = {0.f, 0.f, 0.f, 0.f};
#pragma unroll
    for (int kc = 0; kc < 4; kc++) {
      bf16x8 bw = *(const bf16x8*)(Wb + OPW_OFF + (size_t)(ct * 16 + l15) * H + kc * 32 + g * 8);
      acc0 = __builtin_amdgcn_mfma_f32_16x16x32_bf16(bw, ca[0][kc], acc0, 0, 0, 0);
      acc1 = __builtin_amdgcn_mfma_f32_16x16x32_bf16(bw, ca[1][kc], acc1, 0, 0, 0);
    }
    int oc = ct * 16 + 4 * g;
    float4 bo = *(const float4*)(opb + oc);
#pragma unroll
    for (int rt = 0; rt < 2; rt++) {
      f32x4 acc = rt ? acc1 : acc0;
      int row = row0 + rt * 16 + l15;
      float4 ea = *(const float4*)(edge_attr + (size_t)row * H + oc);
      ushort4 v;
      att[ci][rt][0] = acc[0] + bo.x + ea.x; v.x = f2bf(att[ci][rt][0]);
      att[ci][rt][1] = acc[1] + bo.y + ea.y; v.y = f2bf(att[ci][rt][1]);
      att[ci][rt][2] = acc[2] + bo.z + ea.z; v.z = f2bf(att[ci][rt][2]);
      att[ci][rt][3] = acc[3] + bo.w + ea.w; v.w = f2bf(att[ci][rt][3]);
      *(ushort4*)(attB + (rt * 16 + l15) * IP + oc) = v;
    }
  }
  __syncthreads();

  // phase B: h1 = relu(att @ w1^T + b1)  (4 ct tiles x 2 row-tiles)
  bf16x8 aa[2][4];
#pragma unroll
  for (int rt = 0; rt < 2; rt++)
#pragma unroll
    for (int kc = 0; kc < 4; kc++)
      aa[rt][kc] = *(const bf16x8*)(attB + (rt * 16 + l15) * IP + kc * 32 + g * 8);
#pragma unroll
  for (int ci = 0; ci < 4; ci++) {
    int ct = w * 4 + ci;
    f32x4 acc0 = {0.f, 0.f, 0.f, 0.f}, acc1 = {0.f, 0.f, 0.f, 0.f};
#pragma unroll
    for (int kc = 0; kc < 4; kc++) {
      bf16x8 bw = *(const bf16x8*)(Wb + W1_OFF + (size_t)(ct * 16 + l15) * H + kc * 32 + g * 8);
      acc0 = __builtin_amdgcn_mfma_f32_16x16x32_bf16(bw, aa[0][kc], acc0, 0, 0, 0);
      acc1 = __builtin_amdgcn_mfma_f32_16x16x32_bf16(bw, aa[1][kc], acc1, 0, 0, 0);
    }
    int oc = ct * 16 + 4 * g;
    float4 bb = *(const float4*)(b1 + oc);
#pragma unroll
    for (int rt = 0; rt < 2; rt++) {
      f32x4 acc = rt ? acc1 : acc0;
      ushort4 v;
      v.x = f2bf(fmaxf(acc[0] + bb.x, 0.f)); v.y = f2bf(fmaxf(acc[1] + bb.y, 0.f));
      v.z = f2bf(fmaxf(acc[2] + bb.z, 0.f)); v.w = f2bf(fmaxf(acc[3] + bb.w, 0.f));
      *(ushort4*)(h1L + (rt * 16 + l15) * HP + oc) = v;
    }
  }
  __syncthreads();

  // phase C: out = att + h1 @ w2^T + b2  (same 2 ct tiles, 2 row-tiles)
  bf16x8 ha[2][8];
#pragma unroll
  for (int rt = 0; rt < 2; rt++)
#pragma unroll
    for (int kc = 0; kc < 8; kc++)
      ha[rt][kc] = *(const bf16x8*)(h1L + (rt * 16 + l15) * HP + kc * 32 + g * 8);
#pragma unroll
  for (int ci = 0; ci < 2; ci++) {
    int ct = w * 2 + ci;
    f32x4 acc0 = {0.f, 0.f, 0.f, 0.f}, acc1 = {0.f, 0.f, 0.f, 0.f};
#pragma unroll
    for (int kc = 0; kc < 8; kc++) {
      bf16x8 bw = *(const bf16x8*)(Wb + W2_OFF + (size_t)(ct * 16 + l15) * 2 * H + kc * 32 + g * 8);
      acc0 = __builtin_amdgcn_mfma_f32_16x16x32_bf16(bw, ha[0][kc], acc0, 0, 0, 0);
      acc1 = __builtin_amdgcn_mfma_f32_16x16x32_bf16(bw, ha[1][kc], acc1, 0, 0, 0);
    }
    int oc = ct * 16 + 4 * g;
    float4 bb = *(const float4*)(b2 + oc);
#pragma unroll
    for (int rt = 0; rt < 2; rt++) {
      f32x4 acc = rt ? acc1 : acc0;
      int row = row0 + rt * 16 + l15;
      float4 o;
      o.x = att[ci][rt][0] + acc[0] + bb.x;
      o.y = att[ci][rt][1] + acc[1] + bb.y;
      o.z = att[ci][rt][2] + acc[2] + bb.z;
      o.w = att[ci][rt][3] + acc[3] + bb.w;
      *(float4*)(out + (size_t)row * H + oc) = o;
    }
  }
}

extern "C" void kernel_launch(void* const* d_in, const int* in_sizes, int n_in,
                              void* d_out, int out_size, void* d_ws, size_t ws_size,
                              hipStream_t stream) {
  const float* edge_attr = (const float*)d_in[1];
  const int*   iel       = (const int*)d_in[2];
  const int*   ieb       = (const int*)d_in[3];
  const int*   eb        = (const int*)d_in[4];
  const float* in_proj_w = (const float*)d_in[5];
  const float* in_proj_b = (const float*)d_in[6];
  const float* opw       = (const float*)d_in[7];
  const float* opb       = (const float*)d_in[8];
  const float* w1        = (const float*)d_in[9];
  const float* b1        = (const float*)d_in[10];
  const float* w2        = (const float*)d_in[11];
  const float* b2        = (const float*)d_in[12];
  float* out = (float*)d_out;

  char* ws = (char*)d_ws;
  ushort* CtxB = (ushort*)ws;                     // E*H bf16
  ushort* Wb   = CtxB + (size_t)E * H;            // 131072 bf16 weights
  ushort* Qh   = Wb + W_TOTAL;                    // NH*E*HD bf16
  ushort* Kh   = Qh + (size_t)E * H;              // NH*E*HD bf16
  ushort* Vh   = Kh + (size_t)E * H;              // NH*E*HD bf16

  k_prep<<<dim3(128), dim3(256), 0, stream>>>(in_proj_w, opw, w1, w2, Wb);
  k_proj_all<<<dim3(E / 64), dim3(256), 0, stream>>>(edge_attr, Wb, in_proj_b, Qh, Kh, Vh);
  k_attn_g<<<dim3(B, NH), dim3(256), 0, stream>>>(Qh, Kh, Vh, iel, eb, ieb, in_proj_b, CtxB);
  k_out_ffn_mfma<<<dim3(E / 32), dim3(256), 0, stream>>>(CtxB, edge_attr, eb, Wb, opb, b1, b2, out);
}

// Round 26
// 70.430 us; speedup vs baseline: 1.0561x; 1.0561x over previous
//
#include <hip/hip_runtime.h>
#include <hip/hip_bf16.h>

constexpr int B  = 256;
constexpr int E  = 16384;
constexpr int M  = 65536;
constexpr int H  = 128;
constexpr int NH = 4;
constexpr int HD = 32;
constexpr int LQ = 128;
constexpr int LK = 384;

// bf16 weight buffer offsets (elements)
constexpr int WQ_OFF  = 0;
constexpr int WK_OFF  = 16384;
constexpr int WV_OFF  = 32768;
constexpr int OPW_OFF = 49152;
constexpr int W1_OFF  = 65536;
constexpr int W2_OFF  = 98304;
constexpr int W_TOTAL = 131072;

typedef __attribute__((ext_vector_type(8))) short bf16x8;
typedef __attribute__((ext_vector_type(8))) unsigned short u16x8;
typedef __attribute__((ext_vector_type(4))) float f32x4;

__device__ __forceinline__ ushort f2bf(float x) {
  union { float f; unsigned u; } v; v.f = x;
  unsigned r = (v.u + 0x7FFFu + ((v.u >> 16) & 1u)) >> 16;
  return (ushort)r;
}
__device__ __forceinline__ unsigned pack2bf(float a, float b) {
  return (unsigned)f2bf(a) | ((unsigned)f2bf(b) << 16);
}

// ---------------- K1: bf16 weight prep ----------------
__global__ __launch_bounds__(256) void k_prep(
    const float* __restrict__ in_proj_w, const float* __restrict__ opw,
    const float* __restrict__ w1, const float* __restrict__ w2,
    ushort* __restrict__ Wb) {
  int i = (blockIdx.x * 256 + threadIdx.x) * 4;
  if (i < W_TOTAL) {
    float4 v;
    if (i < OPW_OFF)      v = *(const float4*)(in_proj_w + i);
    else if (i < W1_OFF)  v = *(const float4*)(opw + (i - OPW_OFF));
    else if (i < W2_OFF)  v = *(const float4*)(w1 + (i - W1_OFF));
    else                  v = *(const float4*)(w2 + (i - W2_OFF));
    ushort4 o; o.x = f2bf(v.x); o.y = f2bf(v.y); o.z = f2bf(v.z); o.w = f2bf(v.w);
    *(ushort4*)(Wb + i) = o;
  }
}

// ---------------- K2: dense Q/K/V projection, head-major output ----------------
// grid E/32, 256 threads = 4 waves (round-24 config). Output layout: X[h][e][d].
__global__ __launch_bounds__(256) void k_proj_all(
    const float* __restrict__ edge_attr, const ushort* __restrict__ Wb,
    const float* __restrict__ in_proj_b,
    ushort* __restrict__ Qh, ushort* __restrict__ Kh, ushort* __restrict__ Vh) {
  constexpr int IP = 136;
  __shared__ ushort inL[32 * IP];
  const int t = threadIdx.x;
  const int row0 = blockIdx.x * 32;
  for (int idx = t; idx < 32 * 32; idx += 256) {
    int r = idx >> 5, c = idx & 31;
    float4 v = ((const float4*)(edge_attr + (size_t)(row0 + r) * H))[c];
    ushort4 o; o.x = f2bf(v.x); o.y = f2bf(v.y); o.z = f2bf(v.z); o.w = f2bf(v.w);
    *(ushort4*)(inL + r * IP + c * 4) = o;
  }
  __syncthreads();
  const int w = t >> 6, lane = t & 63, g = lane >> 4, l15 = lane & 15;
  const int wr = (w & 1) * 16, ch = w >> 1;
  bf16x8 a[4];
#pragma unroll
  for (int kc = 0; kc < 4; kc++)
    a[kc] = *(const bf16x8*)(inL + (wr + l15) * IP + kc * 32 + g * 8);
  const int row = row0 + wr + l15;
#pragma unroll
  for (int p = 0; p < 3; p++) {
    const float* bias = in_proj_b + p * H;
    ushort* dst = (p == 0) ? Qh : (p == 1) ? Kh : Vh;
#pragma unroll
    for (int ci = 0; ci < 4; ci++) {
      int ct = ch * 4 + ci;
      f32x4 acc = {0.f, 0.f, 0.f, 0.f};
#pragma unroll
      for (int kc = 0; kc < 4; kc++) {
        bf16x8 bw = *(const bf16x8*)(Wb + p * 16384 + (size_t)(ct * 16 + l15) * H + kc * 32 + g * 8);
        acc = __builtin_amdgcn_mfma_f32_16x16x32_bf16(bw, a[kc], acc, 0, 0, 0);
      }
      int oc = ct * 16 + 4 * g;
      float4 bb = *(const float4*)(bias + oc);
      ushort4 v;
      v.x = f2bf(acc[0] + bb.x); v.y = f2bf(acc[1] + bb.y);
      v.z = f2bf(acc[2] + bb.z); v.w = f2bf(acc[3] + bb.w);
      // head-major: (oc>>5) head, row, (oc&31) channel
      *(ushort4*)(dst + (size_t)(oc >> 5) * E * HD + (size_t)row * HD + (oc & 31)) = v;
    }
  }
}

// ---------------- K3: flash attention; K from global, V^T in LDS ----------------
// grid (B, NH), 512 threads = 8 waves: q-tiles strided by 8 (tail blocks
// with nqt=8 get 1 tile/wave). Segment bounds via inline binary search.
__global__ __launch_bounds__(512, 2) void k_attn_g(
    const ushort* __restrict__ Qh, const ushort* __restrict__ Kh,
    const ushort* __restrict__ Vh, const int* __restrict__ iel,
    const int* __restrict__ eb, const int* __restrict__ ieb,
    const float* __restrict__ in_proj_b, ushort* __restrict__ CtxB) {
  constexpr int VP = 388;
  __shared__ ushort VTl[HD * VP];              // 24832 B
  __shared__ int srcL[LK];                     //  1536 B
  __shared__ int meta[4];

  const int b = blockIdx.x, h = blockIdx.y;
  const int t = threadIdx.x;
  if (t < 4) {
    int target = (t & 1) ? b + 1 : b;
    const int* arr = (t < 2) ? eb : ieb;
    int n = (t < 2) ? E : M;
    int lo = 0, hi = n;
    while (lo < hi) { int mid = (lo + hi) >> 1; if (arr[mid] < target) lo = mid + 1; else hi = mid; }
    meta[t] = lo;
  }
  __syncthreads();
  const int q0 = meta[0], lenq = meta[1] - meta[0];
  const int k0 = meta[2], lenk = meta[3] - meta[2];
  const int nq = lenq < LQ ? lenq : LQ;
  const int nk = lenk < LK ? lenk : LK;
  const int nkc = (nk + 63) & ~63;
  const int nqt = (nq + 15) >> 4;

  const int w = t >> 6, lane = t & 63, g = lane >> 4, l15 = lane & 15;
  const ushort* Qhh = Qh + (size_t)h * E * HD;
  const ushort* Khh = Kh + (size_t)h * E * HD;
  const ushort* Vhh = Vh + (size_t)h * E * HD;
  const int chb = h * HD;

  // resolve gather indices (with LK clip)
  for (int idx = t; idx < nk; idx += 512) {
    int kj = k0 + idx;
    if (lenk > LK && idx == LK - 1) kj = k0 + lenk - 1;
    srcL[idx] = iel[kj];
  }
  __syncthreads();
  // stage V head-slices transposed (indices from srcL)
  for (int idx = t; idx < nk * 4; idx += 512) {
    int row = idx >> 2, c = idx & 3;
    int src = srcL[row];
    u16x8 v = *(const u16x8*)(Vhh + (size_t)src * HD + c * 8);
#pragma unroll
    for (int j = 0; j < 8; j++) VTl[(c * 8 + j) * VP + row] = v[j];
  }
  for (int idx = t; idx < ((nkc - nk) << 5); idx += 512) {
    int d = idx & 31, k = nk + (idx >> 5);
    VTl[d * VP + k] = 0;
  }
  __syncthreads();

  const float scale = 0.17677669529663687f;  // 1/sqrt(32)
  for (int qt = w; qt < nqt; qt += 8) {
    int slot = qt * 16 + l15;
    bool valid = slot < nq;
    int src = q0 + slot;
    if (lenq > LQ && slot == LQ - 1) src = q0 + lenq - 1;
    if (!valid) src = q0;
    bf16x8 bq = *(const bf16x8*)(Qhh + (size_t)src * HD + g * 8);

    f32x4 o0 = {0.f, 0.f, 0.f, 0.f}, o1 = {0.f, 0.f, 0.f, 0.f};
    float m = -3.0e38f, s = 0.f;
    for (int kc = 0; kc < nk; kc += 64) {
      int r0 = kc + l15, r1 = kc + 16 + l15, r2 = kc + 32 + l15, r3 = kc + 48 + l15;
      int s0_ = (r0 < nk) ? srcL[r0] : 0;
      int s1_ = (r1 < nk) ? srcL[r1] : 0;
      int s2_ = (r2 < nk) ? srcL[r2] : 0;
      int s3_ = (r3 < nk) ? srcL[r3] : 0;
      bf16x8 a0 = *(const bf16x8*)(Khh + (size_t)s0_ * HD + g * 8);
      bf16x8 a1 = *(const bf16x8*)(Khh + (size_t)s1_ * HD + g * 8);
      bf16x8 a2 = *(const bf16x8*)(Khh + (size_t)s2_ * HD + g * 8);
      bf16x8 a3 = *(const bf16x8*)(Khh + (size_t)s3_ * HD + g * 8);
      f32x4 z = {0.f, 0.f, 0.f, 0.f};
      f32x4 st0 = __builtin_amdgcn_mfma_f32_16x16x32_bf16(a0, bq, z, 0, 0, 0);
      f32x4 st1 = __builtin_amdgcn_mfma_f32_16x16x32_bf16(a1, bq, z, 0, 0, 0);
      f32x4 st2 = __builtin_amdgcn_mfma_f32_16x16x32_bf16(a2, bq, z, 0, 0, 0);
      f32x4 st3 = __builtin_amdgcn_mfma_f32_16x16x32_bf16(a3, bq, z, 0, 0, 0);
      float p[16];
#pragma unroll
      for (int r = 0; r < 4; r++) {
        p[r]      = (kc + 4 * g + r < nk)      ? st0[r] * scale : -1e30f;
        p[4 + r]  = (kc + 16 + 4 * g + r < nk) ? st1[r] * scale : -1e30f;
        p[8 + r]  = (kc + 32 + 4 * g + r < nk) ? st2[r] * scale : -1e30f;
        p[12 + r] = (kc + 48 + 4 * g + r < nk) ? st3[r] * scale : -1e30f;
      }
      float pm = p[0];
#pragma unroll
      for (int r = 1; r < 16; r++) pm = fmaxf(pm, p[r]);
      pm = fmaxf(pm, __shfl_xor(pm, 16));
      pm = fmaxf(pm, __shfl_xor(pm, 32));
      float mn = fmaxf(m, pm);
      float corr = __expf(m - mn);
      float rs = 0.f;
#pragma unroll
      for (int r = 0; r < 16; r++) { p[r] = __expf(p[r] - mn); rs += p[r]; }
      rs += __shfl_xor(rs, 16);
      rs += __shfl_xor(rs, 32);
      s = s * corr + rs;
      m = mn;
      unsigned pkw[4][2];
#pragma unroll
      for (int i = 0; i < 4; i++) {
        pkw[i][0] = pack2bf(p[4 * i + 0], p[4 * i + 1]);
        pkw[i][1] = pack2bf(p[4 * i + 2], p[4 * i + 3]);
      }
      union { int i[4]; bf16x8 v; } pb0, pb1;
#pragma unroll
      for (int j = 0; j < 4; j++) {
        int sl = (2 * (g & 1) + (j >> 1)) * 16 + l15;
        int a_ = __shfl((int)pkw[0][j & 1], sl);
        int b_ = __shfl((int)pkw[1][j & 1], sl);
        int c_ = __shfl((int)pkw[2][j & 1], sl);
        int d_ = __shfl((int)pkw[3][j & 1], sl);
        pb0.i[j] = (g < 2) ? a_ : b_;
        pb1.i[j] = (g < 2) ? c_ : d_;
      }
      bf16x8 av00 = *(const bf16x8*)(VTl + l15 * VP + kc + 8 * g);
      bf16x8 av01 = *(const bf16x8*)(VTl + l15 * VP + kc + 32 + 8 * g);
      bf16x8 av10 = *(const bf16x8*)(VTl + (16 + l15) * VP + kc + 8 * g);
      bf16x8 av11 = *(const bf16x8*)(VTl + (16 + l15) * VP + kc + 32 + 8 * g);
#pragma unroll
      for (int r = 0; r < 4; r++) { o0[r] *= corr; o1[r] *= corr; }
      o0 = __builtin_amdgcn_mfma_f32_16x16x32_bf16(av00, pb0.v, o0, 0, 0, 0);
      o0 = __builtin_amdgcn_mfma_f32_16x16x32_bf16(av01, pb1.v, o0, 0, 0, 0);
      o1 = __builtin_amdgcn_mfma_f32_16x16x32_bf16(av10, pb0.v, o1, 0, 0, 0);
      o1 = __builtin_amdgcn_mfma_f32_16x16x32_bf16(av11, pb1.v, o1, 0, 0, 0);
    }
    if (valid) {
      int qi = q0 + slot;
      if (lenq > LQ && slot == LQ - 1) qi = q0 + lenq - 1;
      ushort* outp = CtxB + (size_t)qi * H + chb;
      if (nk > 0) {
        float inv = 1.f / s;
        ushort4 v0, v1;
#pragma unroll
        for (int r = 0; r < 4; r++) { ((ushort*)&v0)[r] = f2bf(o0[r] * inv); ((ushort*)&v1)[r] = f2bf(o1[r] * inv); }
        *(ushort4*)(outp + 4 * g) = v0;
        *(ushort4*)(outp + 16 + 4 * g) = v1;
      } else {
        const float* bv = in_proj_b + 2 * H + chb;
        ushort4 v0, v1;
#pragma unroll
        for (int r = 0; r < 4; r++) { ((ushort*)&v0)[r] = f2bf(bv[4 * g + r]); ((ushort*)&v1)[r] = f2bf(bv[16 + 4 * g + r]); }
        *(ushort4*)(outp + 4 * g) = v0;
        *(ushort4*)(outp + 16 + 4 * g) = v1;
      }
    }
  }
}

// ---------------- K4: out-proj + residual + FFN (32-row blocks, 2 row-tiles/wave) ----------------
__global__ __launch_bounds__(256) void k_out_ffn_mfma(
    const ushort* __restrict__ CtxB, const float* __restrict__ edge_attr,
    const int* __restrict__ eb, const ushort* __restrict__ Wb,
    const float* __restrict__ opb, const float* __restrict__ b1,
    const float* __restrict__ b2, float* __restrict__ out) {
  constexpr int IP = 136;  // K=128 pitch
  constexpr int HP = 264;  // K=256 pitch
  __shared__ ushort attB[32 * IP];  // ctx staging, then att bf16 (8704 B)
  __shared__ ushort h1L[32 * HP];   // h1 bf16 (16896 B)
  __shared__ int srcRow[32];
  const int t = threadIdx.x;
  const int row0 = blockIdx.x * 32;

  if (t < 32) {
    int i = row0 + t;
    int bb = eb[i];
    int lo = 0, hi = E;
    while (lo < hi) { int mid = (lo + hi) >> 1; if (eb[mid] < bb) lo = mid + 1; else hi = mid; }
    int qq0 = lo;
    hi = E;
    while (lo < hi) { int mid = (lo + hi) >> 1; if (eb[mid] < bb + 1) lo = mid + 1; else hi = mid; }
    int lenq = lo - qq0;
    int src = i;
    if (lenq > LQ && (i - qq0) >= LQ - 1) src = qq0 + lenq - 1;
    srcRow[t] = src;
  }
  __syncthreads();

  for (int idx = t; idx < 32 * 16; idx += 256) {
    int r = idx >> 4, c = idx & 15;
    *(u16x8*)(attB + r * IP + c * 8) = *(const u16x8*)(CtxB + (size_t)srcRow[r] * H + c * 8);
  }
  __syncthreads();

  const int w = t >> 6, lane = t & 63, g = lane >> 4, l15 = lane & 15;
  bf16x8 ca[2][4];
#pragma unroll
  for (int rt = 0; rt < 2; rt++)
#pragma unroll
    for (int kc = 0; kc < 4; kc++)
      ca[rt][kc] = *(const bf16x8*)(attB + (rt * 16 + l15) * IP + kc * 32 + g * 8);
  __syncthreads();   // attB free for att writes

  // phase A: att = ctx @ opw^T + opb + edge_attr  (2 ct tiles x 2 row-tiles)
  float att[2][2][4];   // [ci][rt][r]
#pragma unroll
  for (int ci = 0; ci < 2; ci++) {
    int ct = w * 2 + ci;
    f32x4 acc0 = {0.f, 0.f, 0.f, 0.f}, acc1 = {0.f, 0.f, 0.f, 0.f};
#pragma unroll
    for (int kc = 0; kc < 4; kc++) {
      bf16x8 bw = *(const bf16x8*)(Wb + OPW_OFF + (size_t)(ct * 16 + l15) * H + kc * 32 + g * 8);
      acc0 = __builtin_amdgcn_mfma_f32_16x16x32_bf16(bw, ca[0][kc], acc0, 0, 0, 0);
      acc1 = __builtin_amdgcn_mfma_f32_16x16x32_bf16(bw, ca[1][kc], acc1, 0, 0, 0);
    }
    int oc = ct * 16 + 4 * g;
    float4 bo = *(const float4*)(opb + oc);
#pragma unroll
    for (int rt = 0; rt < 2; rt++) {
      f32x4 acc = rt ? acc1 : acc0;
      int row = row0 + rt * 16 + l15;
      float4 ea = *(const float4*)(edge_attr + (size_t)row * H + oc);
      ushort4 v;
      att[ci][rt][0] = acc[0] + bo.x + ea.x; v.x = f2bf(att[ci][rt][0]);
      att[ci][rt][1] = acc[1] + bo.y + ea.y; v.y = f2bf(att[ci][rt][1]);
      att[ci][rt][2] = acc[2] + bo.z + ea.z; v.z = f2bf(att[ci][rt][2]);
      att[ci][rt][3] = acc[3] + bo.w + ea.w; v.w = f2bf(att[ci][rt][3]);
      *(ushort4*)(attB + (rt * 16 + l15) * IP + oc) = v;
    }
  }
  __syncthreads();

  // phase B: h1 = relu(att @ w1^T + b1)  (4 ct tiles x 2 row-tiles)
  bf16x8 aa[2][4];
#pragma unroll
  for (int rt = 0; rt < 2; rt++)
#pragma unroll
    for (int kc = 0; kc < 4; kc++)
      aa[rt][kc] = *(const bf16x8*)(attB + (rt * 16 + l15) * IP + kc * 32 + g * 8);
#pragma unroll
  for (int ci = 0; ci < 4; ci++) {
    int ct = w * 4 + ci;
    f32x4 acc0 = {0.f, 0.f, 0.f, 0.f}, acc1 = {0.f, 0.f, 0.f, 0.f};
#pragma unroll
    for (int kc = 0; kc < 4; kc++) {
      bf16x8 bw = *(const bf16x8*)(Wb + W1_OFF + (size_t)(ct * 16 + l15) * H + kc * 32 + g * 8);
      acc0 = __builtin_amdgcn_mfma_f32_16x16x32_bf16(bw, aa[0][kc], acc0, 0, 0, 0);
      acc1 = __builtin_amdgcn_mfma_f32_16x16x32_bf16(bw, aa[1][kc], acc1, 0, 0, 0);
    }
    int oc = ct * 16 + 4 * g;
    float4 bb = *(const float4*)(b1 + oc);
#pragma unroll
    for (int rt = 0; rt < 2; rt++) {
      f32x4 acc = rt ? acc1 : acc0;
      ushort4 v;
      v.x = f2bf(fmaxf(acc[0] + bb.x, 0.f)); v.y = f2bf(fmaxf(acc[1] + bb.y, 0.f));
      v.z = f2bf(fmaxf(acc[2] + bb.z, 0.f)); v.w = f2bf(fmaxf(acc[3] + bb.w, 0.f));
      *(ushort4*)(h1L + (rt * 16 + l15) * HP + oc) = v;
    }
  }
  __syncthreads();

  // phase C: out = att + h1 @ w2^T + b2  (same 2 ct tiles, 2 row-tiles)
  bf16x8 ha[2][8];
#pragma unroll
  for (int rt = 0; rt < 2; rt++)
#pragma unroll
    for (int kc = 0; kc < 8; kc++)
      ha[rt][kc] = *(const bf16x8*)(h1L + (rt * 16 + l15) * HP + kc * 32 + g * 8);
#pragma unroll
  for (int ci = 0; ci < 2; ci++) {
    int ct = w * 2 + ci;
    f32x4 acc0 = {0.f, 0.f, 0.f, 0.f}, acc1 = {0.f, 0.f, 0.f, 0.f};
#pragma unroll
    for (int kc = 0; kc < 8; kc++) {
      bf16x8 bw = *(const bf16x8*)(Wb + W2_OFF + (size_t)(ct * 16 + l15) * 2 * H + kc * 32 + g * 8);
      acc0 = __builtin_amdgcn_mfma_f32_16x16x32_bf16(bw, ha[0][kc], acc0, 0, 0, 0);
      acc1 = __builtin_amdgcn_mfma_f32_16x16x32_bf16(bw, ha[1][kc], acc1, 0, 0, 0);
    }
    int oc = ct * 16 + 4 * g;
    float4 bb = *(const float4*)(b2 + oc);
#pragma unroll
    for (int rt = 0; rt < 2; rt++) {
      f32x4 acc = rt ? acc1 : acc0;
      int row = row0 + rt * 16 + l15;
      float4 o;
      o.x = att[ci][rt][0] + acc[0] + bb.x;
      o.y = att[ci][rt][1] + acc[1] + bb.y;
      o.z = att[ci][rt][2] + acc[2] + bb.z;
      o.w = att[ci][rt][3] + acc[3] + bb.w;
      *(float4*)(out + (size_t)row * H + oc) = o;
    }
  }
}

extern "C" void kernel_launch(void* const* d_in, const int* in_sizes, int n_in,
                              void* d_out, int out_size, void* d_ws, size_t ws_size,
                              hipStream_t stream) {
  const float* edge_attr = (const float*)d_in[1];
  const int*   iel       = (const int*)d_in[2];
  const int*   ieb       = (const int*)d_in[3];
  const int*   eb        = (const int*)d_in[4];
  const float* in_proj_w = (const float*)d_in[5];
  const float* in_proj_b = (const float*)d_in[6];
  const float* opw       = (const float*)d_in[7];
  const float* opb       = (const float*)d_in[8];
  const float* w1        = (const float*)d_in[9];
  const float* b1        = (const float*)d_in[10];
  const float* w2        = (const float*)d_in[11];
  const float* b2        = (const float*)d_in[12];
  float* out = (float*)d_out;

  char* ws = (char*)d_ws;
  ushort* CtxB = (ushort*)ws;                     // E*H bf16
  ushort* Wb   = CtxB + (size_t)E * H;            // 131072 bf16 weights
  ushort* Qh   = Wb + W_TOTAL;                    // NH*E*HD bf16
  ushort* Kh   = Qh + (size_t)E * H;              // NH*E*HD bf16
  ushort* Vh   = Kh + (size_t)E * H;              // NH*E*HD bf16

  k_prep<<<dim3(128), dim3(256), 0, stream>>>(in_proj_w, opw, w1, w2, Wb);
  k_proj_all<<<dim3(E / 32), dim3(256), 0, stream>>>(edge_attr, Wb, in_proj_b, Qh, Kh, Vh);
  k_attn_g<<<dim3(B, NH), dim3(512), 0, stream>>>(Qh, Kh, Vh, iel, eb, ieb, in_proj_b, CtxB);
  k_out_ffn_mfma<<<dim3(E / 32), dim3(256), 0, stream>>>(CtxB, edge_attr, eb, Wb, opb, b1, b2, out);
}